// Round 1
// baseline (389.612 us; speedup 1.0000x reference)
//
#include <hip/hip_runtime.h>

// Problem: B=16, L=128, D=256, O=256
// out[b,i,o] = relu( sum_j adj[b,i,j] * sum_d (text[b,j,d]+dep[b,j,i,d]) * W[d,o] + bias[o] )
// Reassociated: S[b,i,d] = sum_j adj[b,i,j]*(text[b,j,d]+dep[b,j,i,d]); out = relu(S@W + b)
// Memory-bound on the one-shot 268 MB read of dep_embed.

constexpr int Bc = 16, Lc = 128, Dc = 256, Oc = 256;
constexpr int ITILE = 4;   // i-rows per block (one per wave)

__global__ __launch_bounds__(256)
void gc_fused(const float4* __restrict__ text4,   // [B,L,D/4]
              const float*  __restrict__ adj,     // [B,L,L]
              const float4* __restrict__ dep4,    // [B,L,L,D/4]
              const float4* __restrict__ weight4, // [D,O/4]
              const float4* __restrict__ bias4,   // [O/4]
              float4* __restrict__ out4)          // [B,L,O/4]
{
    const int b  = blockIdx.x >> 5;          // 512 blocks / 32 per batch
    const int i0 = (blockIdx.x & 31) * ITILE;
    const int t  = threadIdx.x;
    const int ig = t >> 6;                   // wave id = local i row (0..3)
    const int dg = t & 63;                   // float4 lane over D (0..63)

    __shared__ float s_adj[ITILE][Lc];
    __shared__ float s_S[ITILE][Dc];

    // Stage the 4 adj rows this block needs (4*128 floats, 2 per thread).
    for (int k = t; k < ITILE * Lc; k += 256) {
        int row = k >> 7;        // /128
        int col = k & (Lc - 1);
        s_adj[row][col] = adj[((b * Lc) + i0 + row) * Lc + col];
    }
    __syncthreads();

    const int i = i0 + ig;

    // Phase 1: S[b,i,d4=dg] = sum_j adj[b,i,j]*(text[b,j,dg]+dep[b,j,i,dg])
    float4 acc = {0.f, 0.f, 0.f, 0.f};
    const float4* tb = text4 + (size_t)b * Lc * (Dc / 4) + dg;                 // text[b][j][dg]
    const float4* db = dep4  + ((size_t)b * Lc * Lc + (size_t)i) * (Dc / 4) + dg; // dep[b][j][i][dg]
    #pragma unroll 4
    for (int j = 0; j < Lc; ++j) {
        float  a  = s_adj[ig][j];
        float4 tx = tb[(size_t)j * (Dc / 4)];
        float4 de = db[(size_t)j * Lc * (Dc / 4)];
        acc.x = fmaf(a, tx.x + de.x, acc.x);
        acc.y = fmaf(a, tx.y + de.y, acc.y);
        acc.z = fmaf(a, tx.z + de.z, acc.z);
        acc.w = fmaf(a, tx.w + de.w, acc.w);
    }
    ((float4*)&s_S[ig][0])[dg] = acc;
    __syncthreads();

    // Phase 2: out[b,i,o4=dg] = relu(bias + sum_d S[b,i,d] * W[d][o4])
    float4 oacc = bias4[dg];
    #pragma unroll 4
    for (int d = 0; d < Dc; ++d) {
        float  s = s_S[ig][d];                 // broadcast read (conflict-free)
        float4 w = weight4[d * (Oc / 4) + dg]; // coalesced, L2-resident
        oacc.x = fmaf(s, w.x, oacc.x);
        oacc.y = fmaf(s, w.y, oacc.y);
        oacc.z = fmaf(s, w.z, oacc.z);
        oacc.w = fmaf(s, w.w, oacc.w);
    }
    oacc.x = fmaxf(oacc.x, 0.f);
    oacc.y = fmaxf(oacc.y, 0.f);
    oacc.z = fmaxf(oacc.z, 0.f);
    oacc.w = fmaxf(oacc.w, 0.f);
    out4[((size_t)b * Lc + i) * (Oc / 4) + dg] = oacc;
}

extern "C" void kernel_launch(void* const* d_in, const int* in_sizes, int n_in,
                              void* d_out, int out_size, void* d_ws, size_t ws_size,
                              hipStream_t stream) {
    const float4* text4   = (const float4*)d_in[0]; // [16,128,256] f32
    const float*  adj     = (const float*) d_in[1]; // [16,128,128] f32
    const float4* dep4    = (const float4*)d_in[2]; // [16,128,128,256] f32
    const float4* weight4 = (const float4*)d_in[3]; // [256,256] f32
    const float4* bias4   = (const float4*)d_in[4]; // [256] f32
    float4*       out4    = (float4*)d_out;         // [16,128,256] f32

    dim3 grid(Bc * (Lc / ITILE));   // 16 * 32 = 512 blocks
    dim3 block(256);
    gc_fused<<<grid, block, 0, stream>>>(text4, adj, dep4, weight4, bias4, out4);
}

// Round 2
// 377.314 us; speedup vs baseline: 1.0326x; 1.0326x over previous
//
#include <hip/hip_runtime.h>

// Problem: B=16, L=128, D=256, O=256
// out[b,i,o] = relu( sum_j adj[b,i,j] * sum_d (text[b,j,d]+dep[b,j,i,d]) * W[d,o] + bias[o] )
// Reassociated: S[b,i,d] = sum_j adj[b,i,j]*(text[b,j,d]+dep[b,j,i,d]); out = relu(S@W + b)
// Memory-bound on the one-shot 268 MB read of dep_embed. Roofline ~43 us @ 6.3 TB/s.
//
// R2: one block per (b,i) -> 2048 blocks = 8 blocks/CU = 32 waves/CU (max occupancy).
// 4 waves split the j-sum (32 j each), LDS reduce, then split the d-sum for S@W.

constexpr int Bc = 16, Lc = 128, Dc = 256, Oc = 256;

__global__ __launch_bounds__(256, 8)
void gc_fused(const float4* __restrict__ text4,   // [B,L,D/4]
              const float*  __restrict__ adj,     // [B,L,L]
              const float4* __restrict__ dep4,    // [B,L,L,D/4]
              const float4* __restrict__ weight4, // [D,O/4]
              const float4* __restrict__ bias4,   // [O/4]
              float4* __restrict__ out4)          // [B,L,O/4]
{
    const int b    = blockIdx.x >> 7;     // 2048 blocks = 16 b x 128 i
    const int i    = blockIdx.x & 127;
    const int t    = threadIdx.x;
    const int w    = t >> 6;              // wave id 0..3
    const int lane = t & 63;              // float4 lane over D (and O)

    __shared__ float s_adj[Lc];           // 512 B
    __shared__ float s_part[4][Dc];       // 4 KB  : per-wave partial S
    __shared__ float s_S[Dc];             // 1 KB  : reduced S
    __shared__ float s_po[4][Oc];         // 4 KB  : per-wave partial out

    // Stage this row's adj (128 floats).
    if (t < Lc) s_adj[t] = adj[((size_t)b * Lc + i) * Lc + t];
    __syncthreads();

    // Phase 1: wave w accumulates j in [32w, 32w+32).
    float4 acc = {0.f, 0.f, 0.f, 0.f};
    const int j0 = w * 32;
    const float4* tb = text4 + (size_t)b * Lc * (Dc / 4) + lane;                   // text[b][j][lane]
    const float4* db = dep4  + ((size_t)b * Lc * Lc + (size_t)i) * (Dc / 4) + lane; // dep[b][j][i][lane]
    #pragma unroll 4
    for (int jj = 0; jj < 32; ++jj) {
        const int j = j0 + jj;
        float  a  = s_adj[j];
        float4 tx = tb[(size_t)j * (Dc / 4)];
        float4 de = db[(size_t)j * (size_t)Lc * (Dc / 4)];
        acc.x = fmaf(a, tx.x + de.x, acc.x);
        acc.y = fmaf(a, tx.y + de.y, acc.y);
        acc.z = fmaf(a, tx.z + de.z, acc.z);
        acc.w = fmaf(a, tx.w + de.w, acc.w);
    }
    ((float4*)&s_part[w][0])[lane] = acc;
    __syncthreads();

    // Reduce partial S across the 4 waves: thread t owns d = t.
    s_S[t] = s_part[0][t] + s_part[1][t] + s_part[2][t] + s_part[3][t];
    __syncthreads();

    // Phase 2: wave w sums d in [64w, 64w+64) of S[d]*W[d][o4=lane].
    float4 oacc = {0.f, 0.f, 0.f, 0.f};
    #pragma unroll 8
    for (int k = 0; k < 64; ++k) {
        const int d = w * 64 + k;
        float  s  = s_S[d];                       // LDS broadcast
        float4 wv = weight4[d * (Oc / 4) + lane]; // coalesced, L2-resident
        oacc.x = fmaf(s, wv.x, oacc.x);
        oacc.y = fmaf(s, wv.y, oacc.y);
        oacc.z = fmaf(s, wv.z, oacc.z);
        oacc.w = fmaf(s, wv.w, oacc.w);
    }
    ((float4*)&s_po[w][0])[lane] = oacc;
    __syncthreads();

    // Wave 0: reduce 4 partial outputs, add bias, ReLU, store.
    if (w == 0) {
        float4 r = bias4[lane];
        #pragma unroll
        for (int p = 0; p < 4; ++p) {
            float4 v = ((float4*)&s_po[p][0])[lane];
            r.x += v.x; r.y += v.y; r.z += v.z; r.w += v.w;
        }
        r.x = fmaxf(r.x, 0.f);
        r.y = fmaxf(r.y, 0.f);
        r.z = fmaxf(r.z, 0.f);
        r.w = fmaxf(r.w, 0.f);
        out4[((size_t)b * Lc + i) * (Oc / 4) + lane] = r;
    }
}

extern "C" void kernel_launch(void* const* d_in, const int* in_sizes, int n_in,
                              void* d_out, int out_size, void* d_ws, size_t ws_size,
                              hipStream_t stream) {
    const float4* text4   = (const float4*)d_in[0]; // [16,128,256] f32
    const float*  adj     = (const float*) d_in[1]; // [16,128,128] f32
    const float4* dep4    = (const float4*)d_in[2]; // [16,128,128,256] f32
    const float4* weight4 = (const float4*)d_in[3]; // [256,256] f32
    const float4* bias4   = (const float4*)d_in[4]; // [256] f32
    float4*       out4    = (float4*)d_out;         // [16,128,256] f32

    dim3 grid(Bc * Lc);   // 2048 blocks, one per (b,i)
    dim3 block(256);
    gc_fused<<<grid, block, 0, stream>>>(text4, adj, dep4, weight4, bias4, out4);
}

// Round 3
// 368.470 us; speedup vs baseline: 1.0574x; 1.0240x over previous
//
#include <hip/hip_runtime.h>

// Problem: B=16, L=128, D=256, O=256
// out[b,i,o] = relu( sum_j adj[b,i,j] * sum_d (text[b,j,d]+dep[b,j,i,d]) * W[d,o] + bias[o] )
// Reassociated: S[b,i,d] = sum_j adj[b,i,j]*(text[b,j,d]+dep[b,j,i,d]); out = relu(S@W + b)
// Memory-bound on the one-shot 268 MB read of dep_embed. Roofline ~43 us @ 6.3 TB/s.
//
// R3: block = 512 threads (8 waves) owns an i-PAIR. 1024 blocks = 4 blocks/CU
// = 32 waves/CU (full occupancy). Each wave handles both i's for its j-slice:
//  - dep reads become 2 KB contiguous runs (i0,i0+1 adjacent) -> less scatter
//  - one text load feeds two FMA groups (text L2 traffic halved)
//  - phase 2: one W row read serves two output rows (W L2 traffic halved)

constexpr int Bc = 16, Lc = 128, Dc = 256, Oc = 256;

__global__ __launch_bounds__(512, 8)
void gc_fused(const float4* __restrict__ text4,   // [B,L,D/4]
              const float*  __restrict__ adj,     // [B,L,L]
              const float4* __restrict__ dep4,    // [B,L,L,D/4]
              const float4* __restrict__ weight4, // [D,O/4]
              const float4* __restrict__ bias4,   // [O/4]
              float4* __restrict__ out4)          // [B,L,O/4]
{
    const int b    = blockIdx.x >> 6;     // 1024 blocks = 16 b x 64 i-pairs
    const int i0   = (blockIdx.x & 63) * 2;
    const int t    = threadIdx.x;
    const int w    = t >> 6;              // wave id 0..7
    const int lane = t & 63;              // float4 lane over D (and O)

    __shared__ float s_adj[2][Lc];        // 1 KB : the two adj rows
    __shared__ float s_buf[8][2][Dc];     // 16 KB: per-wave partials (S, then out)
    __shared__ float s_S[2][Dc];          // 2 KB : reduced S rows

    // Stage adj rows i0, i0+1 (256 floats).
    if (t < 2 * Lc) {
        int row = t >> 7, col = t & (Lc - 1);
        s_adj[row][col] = adj[((size_t)b * Lc + i0 + row) * Lc + col];
    }
    __syncthreads();

    // Phase 1: wave w accumulates j in [16w, 16w+16) for BOTH i rows.
    float4 a0 = {0.f, 0.f, 0.f, 0.f};
    float4 a1 = {0.f, 0.f, 0.f, 0.f};
    const int j0 = w * 16;
    const float4* tb = text4 + (size_t)b * Lc * (Dc / 4) + lane;                    // text[b][j][lane]
    const float4* db = dep4  + ((size_t)b * Lc * Lc + (size_t)i0) * (Dc / 4) + lane; // dep[b][j][i0][lane]
    #pragma unroll 4
    for (int jj = 0; jj < 16; ++jj) {
        const int j = j0 + jj;
        float  aj0 = s_adj[0][j];
        float  aj1 = s_adj[1][j];
        float4 tx  = tb[(size_t)j * (Dc / 4)];
        const float4* dp = db + (size_t)j * (size_t)Lc * (Dc / 4);
        float4 d0 = dp[0];          // dep[b][j][i0][lane]
        float4 d1 = dp[Dc / 4];     // dep[b][j][i0+1][lane] — 1 KB later, contiguous pair
        a0.x = fmaf(aj0, tx.x + d0.x, a0.x);
        a0.y = fmaf(aj0, tx.y + d0.y, a0.y);
        a0.z = fmaf(aj0, tx.z + d0.z, a0.z);
        a0.w = fmaf(aj0, tx.w + d0.w, a0.w);
        a1.x = fmaf(aj1, tx.x + d1.x, a1.x);
        a1.y = fmaf(aj1, tx.y + d1.y, a1.y);
        a1.z = fmaf(aj1, tx.z + d1.z, a1.z);
        a1.w = fmaf(aj1, tx.w + d1.w, a1.w);
    }
    ((float4*)&s_buf[w][0][0])[lane] = a0;
    ((float4*)&s_buf[w][1][0])[lane] = a1;
    __syncthreads();

    // Reduce partial S across 8 waves: thread t owns (i = t>>8, d = t&255).
    {
        const int ii = t >> 8, d = t & (Dc - 1);
        float s = 0.f;
        #pragma unroll
        for (int p = 0; p < 8; ++p) s += s_buf[p][ii][d];
        s_S[ii][d] = s;
    }
    __syncthreads();   // also guards s_buf reuse below

    // Phase 2: wave w sums d in [32w, 32w+32) of S[d]*W[d][o4=lane], both i.
    float4 o0 = {0.f, 0.f, 0.f, 0.f};
    float4 o1 = {0.f, 0.f, 0.f, 0.f};
    #pragma unroll 8
    for (int k = 0; k < 32; ++k) {
        const int d = w * 32 + k;
        float4 wv = weight4[d * (Oc / 4) + lane]; // one W row read serves 2 output rows
        float  s0 = s_S[0][d];                    // LDS broadcast
        float  s1 = s_S[1][d];
        o0.x = fmaf(s0, wv.x, o0.x);
        o0.y = fmaf(s0, wv.y, o0.y);
        o0.z = fmaf(s0, wv.z, o0.z);
        o0.w = fmaf(s0, wv.w, o0.w);
        o1.x = fmaf(s1, wv.x, o1.x);
        o1.y = fmaf(s1, wv.y, o1.y);
        o1.z = fmaf(s1, wv.z, o1.z);
        o1.w = fmaf(s1, wv.w, o1.w);
    }
    ((float4*)&s_buf[w][0][0])[lane] = o0;
    ((float4*)&s_buf[w][1][0])[lane] = o1;
    __syncthreads();

    // Final: 128 threads reduce 8 partial outputs, add bias, ReLU, store.
    if (t < 2 * 64) {
        const int ii = t >> 6, l = t & 63;
        float4 r = bias4[l];
        #pragma unroll
        for (int p = 0; p < 8; ++p) {
            float4 v = ((float4*)&s_buf[p][ii][0])[l];
            r.x += v.x; r.y += v.y; r.z += v.z; r.w += v.w;
        }
        r.x = fmaxf(r.x, 0.f);
        r.y = fmaxf(r.y, 0.f);
        r.z = fmaxf(r.z, 0.f);
        r.w = fmaxf(r.w, 0.f);
        out4[((size_t)b * Lc + i0 + ii) * (Oc / 4) + l] = r;
    }
}

extern "C" void kernel_launch(void* const* d_in, const int* in_sizes, int n_in,
                              void* d_out, int out_size, void* d_ws, size_t ws_size,
                              hipStream_t stream) {
    const float4* text4   = (const float4*)d_in[0]; // [16,128,256] f32
    const float*  adj     = (const float*) d_in[1]; // [16,128,128] f32
    const float4* dep4    = (const float4*)d_in[2]; // [16,128,128,256] f32
    const float4* weight4 = (const float4*)d_in[3]; // [256,256] f32
    const float4* bias4   = (const float4*)d_in[4]; // [256] f32
    float4*       out4    = (float4*)d_out;         // [16,128,256] f32

    dim3 grid(Bc * (Lc / 2));   // 1024 blocks, one per (b, i-pair)
    dim3 block(512);
    gc_fused<<<grid, block, 0, stream>>>(text4, adj, dep4, weight4, bias4, out4);
}